// Round 7
// baseline (145.555 us; speedup 1.0000x reference)
//
#include <hip/hip_runtime.h>
#include <hip/hip_bf16.h>
#include <stdint.h>

#define GAT_ALPHA 0.2f
#define LOG2E 1.4426950408889634f

typedef __attribute__((ext_vector_type(8))) short bf16x8;
typedef __attribute__((ext_vector_type(8))) unsigned short ushort8;
typedef __attribute__((ext_vector_type(4))) float f32x4;
typedef __attribute__((ext_vector_type(4))) unsigned int u32x4;

#if __has_builtin(__builtin_amdgcn_exp2f)
#define EXP2F(x) __builtin_amdgcn_exp2f(x)
#else
#define EXP2F(x) exp2f(x)
#endif

// D.lo = bf16(a), D.hi = bf16(b)  (r6-validated)
static __device__ __forceinline__ unsigned int cvt_pk_bf16(float a, float b) {
    unsigned int r;
    asm("v_cvt_pk_bf16_f32 %0, %1, %2" : "=v"(r) : "v"(a), "v"(b));
    return r;
}

// ---------------- K0: pack adjacency int32 -> bitmask (validated r1) -------
__global__ __launch_bounds__(256) void k_pack_adj(const int* __restrict__ adj,
                                                  unsigned long long* __restrict__ packed,
                                                  int nwords) {
    int gid = blockIdx.x * 256 + threadIdx.x;
    int wid = gid >> 6;               // one 64-bit word per wave
    int lane = threadIdx.x & 63;
    if (wid >= nwords) return;
    int v = adj[(size_t)wid * 64 + lane];
    unsigned long long m = __ballot(v > 0);
    if (lane == 0) packed[wid] = m;
}

// ---------------- K1: Wh = h@W[h]; Wh1/Wh2 (scaled log2e); whT (validated r1)
__global__ __launch_bounds__(256) void k_wh(const float* __restrict__ hmat,   // [4096][256]
                                            const float* __restrict__ Wmat,   // [8][256][32]
                                            const float* __restrict__ avec,   // [8][64]
                                            float* __restrict__ wh1s,         // [8][4096]
                                            float* __restrict__ wh2s,         // [8][4096]
                                            unsigned short* __restrict__ whT) // [8][32][4096]
{
    const int head = blockIdx.y;
    const int nbase = blockIdx.x * 64;
    const int t = threadIdx.x;
    const int d = t & 31, nl = t >> 5;

    __shared__ float WT[32][260];
    __shared__ float hl[8][256];
    __shared__ float tr[64][33];

    #pragma unroll
    for (int k = 0; k < 32; ++k) {
        int idx = t + k * 256;
        int ii = idx >> 5, dd = idx & 31;
        WT[dd][ii] = Wmat[(head * 256 + ii) * 32 + dd];
    }
    float a1 = avec[head * 64 + d];
    float a2 = avec[head * 64 + 32 + d];

    for (int c = 0; c < 8; ++c) {
        __syncthreads();
        {
            const float4* src = (const float4*)&hmat[(size_t)(nbase + c * 8 + nl) * 256 + d * 8];
            float4* dst = (float4*)&hl[nl][d * 8];
            dst[0] = src[0];
            dst[1] = src[1];
        }
        __syncthreads();
        float acc = 0.f;
        #pragma unroll 8
        for (int i = 0; i < 256; i += 4) {
            float4 wv = *(const float4*)&WT[d][i];
            float4 hv = *(const float4*)&hl[nl][i];
            acc += hv.x * wv.x;
            acc += hv.y * wv.y;
            acc += hv.z * wv.z;
            acc += hv.w * wv.w;
        }
        float v1 = acc * a1;
        float v2 = acc * a2;
        #pragma unroll
        for (int s = 1; s < 32; s <<= 1) {
            v1 += __shfl_xor(v1, s);
            v2 += __shfl_xor(v2, s);
        }
        int node = nbase + c * 8 + nl;
        if (d == 0) {
            wh1s[head * 4096 + node] = v1 * LOG2E;
            wh2s[head * 4096 + node] = v2 * LOG2E;
        }
        tr[c * 8 + nl][d] = acc;
    }
    __syncthreads();
    int dp = t >> 3, chunk = t & 7;
    ushort8 vv;
    #pragma unroll
    for (int k = 0; k < 8; ++k) {
        __hip_bfloat16 b = __float2bfloat16(tr[chunk * 8 + k][dp]);
        vv[k] = __builtin_bit_cast(unsigned short, b);
    }
    *(ushort8*)&whT[((size_t)(head * 32 + dp)) * 4096 + nbase + chunk * 8] = vv;
}

// ---------------- K2: fused masked softmax + PV via bf16 MFMA --------------
// grid (256, 8), 256 thr = 4 waves (r5-proven: block = 16 rows, wave w =
// j-quarter). No wh2 LDS staging (w2 read from global, L1-resident) ->
// LDS ~9.3KB -> 8 blocks/CU (grid cap) -> 32 waves/CU.
__global__ __launch_bounds__(256, 8) void k_attn(const unsigned int* __restrict__ adj32, // [4096][128]
                                                 const float* __restrict__ wh1s,
                                                 const float* __restrict__ wh2s,
                                                 const unsigned short* __restrict__ whT,
                                                 float* __restrict__ out) {              // [4096][256]
    const int head = blockIdx.y;
    const int rowbase = blockIdx.x * 16;
    const int t = threadIdx.x;
    const int w = t >> 6;        // j-quarter
    const int lane = t & 63;
    const int r = lane & 15;     // MFMA A row / B col
    const int q = lane >> 4;     // k-quarter
    const int row = rowbase + r;

    __shared__ float wmxb[4];
    __shared__ f32x4 red[3][64][3];

    // per-head max of wh2 (global reads; 16 floats/thread, butterfly reduce)
    const float* wh2p = &wh2s[(size_t)head * 4096];
    float lm = -INFINITY;
    #pragma unroll
    for (int kk = 0; kk < 4; ++kk) {
        float4 v = *(const float4*)&wh2p[kk * 1024 + t * 4];
        lm = fmaxf(fmaxf(lm, fmaxf(v.x, v.y)), fmaxf(v.z, v.w));
    }
    #pragma unroll
    for (int s = 1; s < 64; s <<= 1) lm = fmaxf(lm, __shfl_xor(lm, s));
    if (lane == 0) wmxb[w] = lm;
    __syncthreads();
    const float wm = fmaxf(fmaxf(wmxb[0], wmxb[1]), fmaxf(wmxb[2], wmxb[3]));

    // per-row constants (log2-scaled domain; m >= lrelu(score) for all j)
    const float wh1 = wh1s[(size_t)head * 4096 + row];
    const float sm0 = wh1 + wm;
    const float m = fmaxf(sm0, GAT_ALPHA * sm0);
    const float wh1m = wh1 - m;
    const float c2 = GAT_ALPHA * wh1 - m;

    f32x4 acc0 = {0.f, 0.f, 0.f, 0.f};
    f32x4 acc1 = {0.f, 0.f, 0.f, 0.f};
    f32x4 accd = {0.f, 0.f, 0.f, 0.f};

    const u32x4 onesu = {0x3F803F80u, 0x3F803F80u, 0x3F803F80u, 0x3F803F80u};
    const bf16x8 ones = __builtin_bit_cast(bf16x8, onesu);

    const unsigned short* bp0 = &whT[((size_t)head * 32 + r) * 4096];
    const unsigned short* bp1 = &whT[((size_t)head * 32 + 16 + r) * 4096];
    const unsigned int* arow = adj32 + (size_t)row * 128 + w * 32;

    #pragma unroll 4
    for (int kt = 0; kt < 32; ++kt) {
        const int jb = w * 1024 + kt * 32 + q * 8;
        bf16x8 b0 = *(const bf16x8*)&bp0[jb];
        bf16x8 b1 = *(const bf16x8*)&bp1[jb];
        unsigned int bits = (arow[kt] >> (q * 8)) & 0xffu;
        float w2[8];
        *(float4*)&w2[0] = *(const float4*)&wh2p[jb];
        *(float4*)&w2[4] = *(const float4*)&wh2p[jb + 4];

        float p[8];
        #pragma unroll
        for (int b = 0; b < 8; ++b) {
            float u = wh1m + w2[b];                       // s - m   (s>0 case)
            float tv = fmaf(GAT_ALPHA, w2[b], c2);        // a*s - m (s<0 case)
            float s = fmaxf(u, tv);                       // lrelu(s) - m, <= 0
            float pe = EXP2F(s);
            p[b] = (bits & (1u << b)) ? pe : 0.f;         // mask
        }
        u32x4 pk = { cvt_pk_bf16(p[0], p[1]), cvt_pk_bf16(p[2], p[3]),
                     cvt_pk_bf16(p[4], p[5]), cvt_pk_bf16(p[6], p[7]) };
        bf16x8 af = __builtin_bit_cast(bf16x8, pk);
        acc0 = __builtin_amdgcn_mfma_f32_16x16x32_bf16(af, b0, acc0, 0, 0, 0);
        acc1 = __builtin_amdgcn_mfma_f32_16x16x32_bf16(af, b1, acc1, 0, 0, 0);
        accd = __builtin_amdgcn_mfma_f32_16x16x32_bf16(af, ones, accd, 0, 0, 0);
    }

    // combine j-quarters: waves 1..3 publish, wave 0 finalizes (r5-validated)
    __syncthreads();
    if (w != 0) {
        red[w - 1][lane][0] = acc0;
        red[w - 1][lane][1] = acc1;
        red[w - 1][lane][2] = accd;
    }
    __syncthreads();
    if (w == 0) {
        #pragma unroll
        for (int jj = 0; jj < 3; ++jj) {
            acc0 += red[jj][lane][0];
            acc1 += red[jj][lane][1];
            accd += red[jj][lane][2];
        }
        // C/D layout (m89-verified): lane holds D[4q+i][r]
        #pragma unroll
        for (int i = 0; i < 4; ++i) {
            float inv = 1.0f / accd[i];
            int orow = rowbase + 4 * q + i;
            out[(size_t)orow * 256 + head * 32 + r]      = acc0[i] * inv;
            out[(size_t)orow * 256 + head * 32 + 16 + r] = acc1[i] * inv;
        }
    }
}

extern "C" void kernel_launch(void* const* d_in, const int* in_sizes, int n_in,
                              void* d_out, int out_size, void* d_ws, size_t ws_size,
                              hipStream_t stream) {
    const float* h   = (const float*)d_in[0];
    const int*   adj = (const int*)d_in[1];
    const float* W   = (const float*)d_in[2];
    const float* a   = (const float*)d_in[3];
    float* out = (float*)d_out;

    char* ws = (char*)d_ws;
    unsigned long long* packed = (unsigned long long*)ws;                       // 2 MB
    float* wh1s = (float*)(ws + (2 << 20));                                     // 128 KB
    float* wh2s = (float*)(ws + (2 << 20) + (128 << 10));                       // 128 KB
    unsigned short* whT = (unsigned short*)(ws + (2 << 20) + (256 << 10));      // 2 MB

    const int nwords = 4096 * 64;
    k_pack_adj<<<nwords * 64 / 256, 256, 0, stream>>>(adj, packed, nwords);
    k_wh<<<dim3(64, 8), 256, 0, stream>>>(h, W, a, wh1s, wh2s, whT);
    k_attn<<<dim3(256, 8), 256, 0, stream>>>((const unsigned int*)packed, wh1s, wh2s, whT, out);
}

// Round 8
// 99.983 us; speedup vs baseline: 1.4558x; 1.4558x over previous
//
#include <hip/hip_runtime.h>
#include <hip/hip_bf16.h>
#include <stdint.h>

#define GAT_ALPHA 0.2f
#define LOG2E 1.4426950408889634f

typedef __attribute__((ext_vector_type(8))) short bf16x8;
typedef __attribute__((ext_vector_type(8))) unsigned short ushort8;
typedef __attribute__((ext_vector_type(4))) float f32x4;
typedef __attribute__((ext_vector_type(4))) unsigned int u32x4;

#if __has_builtin(__builtin_amdgcn_exp2f)
#define EXP2F(x) __builtin_amdgcn_exp2f(x)
#else
#define EXP2F(x) exp2f(x)
#endif

// D.lo = bf16(a), D.hi = bf16(b)  (r6-validated)
static __device__ __forceinline__ unsigned int cvt_pk_bf16(float a, float b) {
    unsigned int r;
    asm("v_cvt_pk_bf16_f32 %0, %1, %2" : "=v"(r) : "v"(a), "v"(b));
    return r;
}

// ---------------- K0: pack adjacency int32 -> bitmask (validated r1) -------
__global__ __launch_bounds__(256) void k_pack_adj(const int* __restrict__ adj,
                                                  unsigned long long* __restrict__ packed,
                                                  int nwords) {
    int gid = blockIdx.x * 256 + threadIdx.x;
    int wid = gid >> 6;               // one 64-bit word per wave
    int lane = threadIdx.x & 63;
    if (wid >= nwords) return;
    int v = adj[(size_t)wid * 64 + lane];
    unsigned long long m = __ballot(v > 0);
    if (lane == 0) packed[wid] = m;
}

// ---------------- K1: Wh = h@W[h]; Wh1/Wh2 (scaled log2e); whT (validated r1)
__global__ __launch_bounds__(256) void k_wh(const float* __restrict__ hmat,   // [4096][256]
                                            const float* __restrict__ Wmat,   // [8][256][32]
                                            const float* __restrict__ avec,   // [8][64]
                                            float* __restrict__ wh1s,         // [8][4096]
                                            float* __restrict__ wh2s,         // [8][4096]
                                            unsigned short* __restrict__ whT) // [8][32][4096]
{
    const int head = blockIdx.y;
    const int nbase = blockIdx.x * 64;
    const int t = threadIdx.x;
    const int d = t & 31, nl = t >> 5;

    __shared__ float WT[32][260];
    __shared__ float hl[8][256];
    __shared__ float tr[64][33];

    #pragma unroll
    for (int k = 0; k < 32; ++k) {
        int idx = t + k * 256;
        int ii = idx >> 5, dd = idx & 31;
        WT[dd][ii] = Wmat[(head * 256 + ii) * 32 + dd];
    }
    float a1 = avec[head * 64 + d];
    float a2 = avec[head * 64 + 32 + d];

    for (int c = 0; c < 8; ++c) {
        __syncthreads();
        {
            const float4* src = (const float4*)&hmat[(size_t)(nbase + c * 8 + nl) * 256 + d * 8];
            float4* dst = (float4*)&hl[nl][d * 8];
            dst[0] = src[0];
            dst[1] = src[1];
        }
        __syncthreads();
        float acc = 0.f;
        #pragma unroll 8
        for (int i = 0; i < 256; i += 4) {
            float4 wv = *(const float4*)&WT[d][i];
            float4 hv = *(const float4*)&hl[nl][i];
            acc += hv.x * wv.x;
            acc += hv.y * wv.y;
            acc += hv.z * wv.z;
            acc += hv.w * wv.w;
        }
        float v1 = acc * a1;
        float v2 = acc * a2;
        #pragma unroll
        for (int s = 1; s < 32; s <<= 1) {
            v1 += __shfl_xor(v1, s);
            v2 += __shfl_xor(v2, s);
        }
        int node = nbase + c * 8 + nl;
        if (d == 0) {
            wh1s[head * 4096 + node] = v1 * LOG2E;
            wh2s[head * 4096 + node] = v2 * LOG2E;
        }
        tr[c * 8 + nl][d] = acc;
    }
    __syncthreads();
    int dp = t >> 3, chunk = t & 7;
    ushort8 vv;
    #pragma unroll
    for (int k = 0; k < 8; ++k) {
        __hip_bfloat16 b = __float2bfloat16(tr[chunk * 8 + k][dp]);
        vv[k] = __builtin_bit_cast(unsigned short, b);
    }
    *(ushort8*)&whT[((size_t)(head * 32 + dp)) * 4096 + nbase + chunk * 8] = vv;
}

// ---------------- K2: fused masked softmax + PV via bf16 MFMA --------------
// grid (128, 8), 256 thr = 4 waves. Block = 32 rows; wave w -> row-tile
// rt=w&1 (16 rows), j-half jh=w>>1 (r2-validated split/reduction).
// Flash-style: 16 steps x 128-j tiles; whT + wh2 staged in LDS each step so
// the MFMA loop is LDS-fed (TA-issue pressure was r7's bottleneck).
__global__ __launch_bounds__(256, 4) void k_attn(const unsigned long long* __restrict__ adj64, // [4096][64]
                                                 const float* __restrict__ wh1s,
                                                 const float* __restrict__ wh2s,
                                                 const unsigned short* __restrict__ whT,
                                                 float* __restrict__ out) {                    // [4096][256]
    const int head = blockIdx.y;
    const int rowbase = blockIdx.x * 32;
    const int t = threadIdx.x;
    const int w = t >> 6;
    const int lane = t & 63;
    const int rt = w & 1;        // row-tile
    const int jh = w >> 1;       // j-half
    const int r = lane & 15;     // MFMA A row / B col
    const int q = lane >> 4;     // k-quarter
    const int row = rowbase + rt * 16 + r;

    __shared__ unsigned short whTl[2][32][136];   // [half][d][j], row 272B (pad)
    __shared__ float wh2t[2][128];
    __shared__ float wmxb[4];
    __shared__ f32x4 red[2][64][3];

    // per-head max of wh2 (r7-validated prepass)
    const float* wh2p = &wh2s[(size_t)head * 4096];
    float lm = -INFINITY;
    #pragma unroll
    for (int kk = 0; kk < 4; ++kk) {
        float4 v = *(const float4*)&wh2p[kk * 1024 + t * 4];
        lm = fmaxf(fmaxf(lm, fmaxf(v.x, v.y)), fmaxf(v.z, v.w));
    }
    #pragma unroll
    for (int s = 1; s < 64; s <<= 1) lm = fmaxf(lm, __shfl_xor(lm, s));
    if (lane == 0) wmxb[w] = lm;
    __syncthreads();
    const float wm = fmaxf(fmaxf(wmxb[0], wmxb[1]), fmaxf(wmxb[2], wmxb[3]));

    // per-row constants (r6-validated math, log2-scaled domain)
    const float wh1 = wh1s[(size_t)head * 4096 + row];
    const float sm0 = wh1 + wm;
    const float m = fmaxf(sm0, GAT_ALPHA * sm0);
    const float wh1m = wh1 - m;
    const float c2 = GAT_ALPHA * wh1 - m;

    f32x4 acc0 = {0.f, 0.f, 0.f, 0.f};
    f32x4 acc1 = {0.f, 0.f, 0.f, 0.f};
    f32x4 accd = {0.f, 0.f, 0.f, 0.f};

    const u32x4 onesu = {0x3F803F80u, 0x3F803F80u, 0x3F803F80u, 0x3F803F80u};
    const bf16x8 ones = __builtin_bit_cast(bf16x8, onesu);

    // staging indices: thread t loads d-row sd, 32B chunk sc, both halves
    const int sd = t >> 3;
    const int sc = t & 7;
    const unsigned short* gwh = &whT[((size_t)head * 32 + sd) * 4096 + sc * 16];
    const unsigned long long* arow = adj64 + (size_t)row * 64 + jh * 32;

    for (int step = 0; step < 16; ++step) {
        __syncthreads();   // previous tile fully consumed
        #pragma unroll
        for (int hh = 0; hh < 2; ++hh) {
            const uint4* s = (const uint4*)&gwh[hh * 2048 + step * 128];
            uint4* dvec = (uint4*)&whTl[hh][sd][sc * 16];
            dvec[0] = s[0];
            dvec[1] = s[1];
        }
        if (t < 64) {
            int hh = t >> 5, ii = (t & 31) * 4;
            *(float4*)&wh2t[hh][ii] = *(const float4*)&wh2p[hh * 2048 + step * 128 + ii];
        }
        __syncthreads();   // tile ready

        const unsigned long long au0 = arow[step * 2];
        const unsigned long long au1 = arow[step * 2 + 1];

        #pragma unroll
        for (int kk = 0; kk < 4; ++kk) {
            const int jl = kk * 32 + q * 8;
            bf16x8 b0 = *(const bf16x8*)&whTl[jh][r][jl];
            bf16x8 b1 = *(const bf16x8*)&whTl[jh][16 + r][jl];
            unsigned int bits =
                (unsigned int)(((kk < 2 ? au0 : au1) >> ((kk & 1) * 32 + q * 8)) & 0xffull);
            float w2[8];
            *(float4*)&w2[0] = *(const float4*)&wh2t[jh][jl];
            *(float4*)&w2[4] = *(const float4*)&wh2t[jh][jl + 4];

            float p[8];
            #pragma unroll
            for (int b = 0; b < 8; ++b) {
                float u = wh1m + w2[b];                  // s - m   (s>0 case)
                float tv = fmaf(GAT_ALPHA, w2[b], c2);   // a*s - m (s<0 case)
                float s = fmaxf(u, tv);                  // lrelu(s) - m, <= 0
                float pe = EXP2F(s);
                p[b] = (bits & (1u << b)) ? pe : 0.f;    // mask
            }
            u32x4 pk = { cvt_pk_bf16(p[0], p[1]), cvt_pk_bf16(p[2], p[3]),
                         cvt_pk_bf16(p[4], p[5]), cvt_pk_bf16(p[6], p[7]) };
            bf16x8 af = __builtin_bit_cast(bf16x8, pk);
            acc0 = __builtin_amdgcn_mfma_f32_16x16x32_bf16(af, b0, acc0, 0, 0, 0);
            acc1 = __builtin_amdgcn_mfma_f32_16x16x32_bf16(af, b1, acc1, 0, 0, 0);
            accd = __builtin_amdgcn_mfma_f32_16x16x32_bf16(af, ones, accd, 0, 0, 0);
        }
    }

    // combine j-halves (r2-validated): jh=1 publish, jh=0 finalize
    if (jh == 1) {
        red[rt][lane][0] = acc0;
        red[rt][lane][1] = acc1;
        red[rt][lane][2] = accd;
    }
    __syncthreads();
    if (jh == 0) {
        acc0 += red[rt][lane][0];
        acc1 += red[rt][lane][1];
        accd += red[rt][lane][2];
        // C/D layout (m89-verified): lane holds D[4q+i][r]
        #pragma unroll
        for (int i = 0; i < 4; ++i) {
            float inv = 1.0f / accd[i];
            int orow = rowbase + rt * 16 + 4 * q + i;
            out[(size_t)orow * 256 + head * 32 + r]      = acc0[i] * inv;
            out[(size_t)orow * 256 + head * 32 + 16 + r] = acc1[i] * inv;
        }
    }
}

extern "C" void kernel_launch(void* const* d_in, const int* in_sizes, int n_in,
                              void* d_out, int out_size, void* d_ws, size_t ws_size,
                              hipStream_t stream) {
    const float* h   = (const float*)d_in[0];
    const int*   adj = (const int*)d_in[1];
    const float* W   = (const float*)d_in[2];
    const float* a   = (const float*)d_in[3];
    float* out = (float*)d_out;

    char* ws = (char*)d_ws;
    unsigned long long* packed = (unsigned long long*)ws;                       // 2 MB
    float* wh1s = (float*)(ws + (2 << 20));                                     // 128 KB
    float* wh2s = (float*)(ws + (2 << 20) + (128 << 10));                       // 128 KB
    unsigned short* whT = (unsigned short*)(ws + (2 << 20) + (256 << 10));      // 2 MB

    const int nwords = 4096 * 64;
    k_pack_adj<<<nwords * 64 / 256, 256, 0, stream>>>(adj, packed, nwords);
    k_wh<<<dim3(64, 8), 256, 0, stream>>>(h, W, a, wh1s, wh2s, whT);
    k_attn<<<dim3(128, 8), 256, 0, stream>>>(packed, wh1s, wh2s, whT, out);
}

// Round 9
// 86.655 us; speedup vs baseline: 1.6797x; 1.1538x over previous
//
#include <hip/hip_runtime.h>
#include <hip/hip_bf16.h>
#include <stdint.h>

#define GAT_ALPHA 0.2f
#define LOG2E 1.4426950408889634f

typedef __attribute__((ext_vector_type(8))) short bf16x8;
typedef __attribute__((ext_vector_type(8))) unsigned short ushort8;
typedef __attribute__((ext_vector_type(4))) float f32x4;
typedef __attribute__((ext_vector_type(4))) unsigned int u32x4;

#if __has_builtin(__builtin_amdgcn_exp2f)
#define EXP2F(x) __builtin_amdgcn_exp2f(x)
#else
#define EXP2F(x) exp2f(x)
#endif

// D.lo = bf16(a), D.hi = bf16(b)  (empirically confirmed by r6 passing:
// A-frag built with arg0->lo matches B's natural element order)
static __device__ __forceinline__ unsigned int cvt_pk_bf16(float a, float b) {
    unsigned int r;
    asm("v_cvt_pk_bf16_f32 %0, %1, %2" : "=v"(r) : "v"(a), "v"(b));
    return r;
}

// ---------------- K0: pack adjacency int32 -> bitmask (validated r1) -------
__global__ __launch_bounds__(256) void k_pack_adj(const int* __restrict__ adj,
                                                  unsigned long long* __restrict__ packed,
                                                  int nwords) {
    int gid = blockIdx.x * 256 + threadIdx.x;
    int wid = gid >> 6;               // one 64-bit word per wave
    int lane = threadIdx.x & 63;
    if (wid >= nwords) return;
    int v = adj[(size_t)wid * 64 + lane];
    unsigned long long m = __ballot(v > 0);
    if (lane == 0) packed[wid] = m;
}

// ---------------- K0b: W [8][256][32] f32 -> wbfT [8][32][256] bf16 --------
__global__ __launch_bounds__(256) void k_cvtW(const float* __restrict__ W,
                                              unsigned short* __restrict__ wbfT) {
    int idx = (blockIdx.x * 256 + threadIdx.x) * 8;   // over 65536 elements
    int hd = idx >> 8;                                 // head*32 + d
    int i0 = idx & 255;
    int hh = hd >> 5, dd = hd & 31;
    float v[8];
    #pragma unroll
    for (int k = 0; k < 8; ++k) v[k] = W[((size_t)hh * 256 + i0 + k) * 32 + dd];
    u32x4 o = { cvt_pk_bf16(v[0], v[1]), cvt_pk_bf16(v[2], v[3]),
                cvt_pk_bf16(v[4], v[5]), cvt_pk_bf16(v[6], v[7]) };
    *(u32x4*)&wbfT[idx] = o;
}

// ---------------- K1: Wh via bf16 MFMA (h converted on the fly) ------------
// grid (64, 8), 256 thr = 4 waves; wave w -> nodes node0..node0+16.
// No LDS, no barriers. A and B frags use the same (q,b)->k map, so the HW
// k-permutation cancels; C/D layout is the m89-verified one.
__global__ __launch_bounds__(256) void k_wh2(const float* __restrict__ hmat,      // [4096][256]
                                             const unsigned short* __restrict__ wbfT, // [8][32][256]
                                             const float* __restrict__ avec,      // [8][64]
                                             float* __restrict__ wh1s,            // [8][4096] *log2e
                                             float* __restrict__ wh2s,            // [8][4096] *log2e
                                             unsigned short* __restrict__ whT) {  // [8][32][4096]
    const int head = blockIdx.y;
    const int nbase = blockIdx.x * 64;
    const int t = threadIdx.x, w = t >> 6, lane = t & 63;
    const int r = lane & 15, q = lane >> 4;
    const int node0 = nbase + w * 16;

    f32x4 acc0 = {0.f, 0.f, 0.f, 0.f};
    f32x4 acc1 = {0.f, 0.f, 0.f, 0.f};
    const float* arow = &hmat[(size_t)(node0 + r) * 256];
    const unsigned short* b0p = &wbfT[((size_t)head * 32 + r) * 256];
    const unsigned short* b1p = b0p + 16 * 256;
    #pragma unroll
    for (int kt = 0; kt < 8; ++kt) {
        const int ko = kt * 32 + q * 8;
        float4 h0 = *(const float4*)&arow[ko];
        float4 h1 = *(const float4*)&arow[ko + 4];
        u32x4 ap = { cvt_pk_bf16(h0.x, h0.y), cvt_pk_bf16(h0.z, h0.w),
                     cvt_pk_bf16(h1.x, h1.y), cvt_pk_bf16(h1.z, h1.w) };
        bf16x8 af = __builtin_bit_cast(bf16x8, ap);
        bf16x8 b0 = *(const bf16x8*)&b0p[ko];
        bf16x8 b1 = *(const bf16x8*)&b1p[ko];
        acc0 = __builtin_amdgcn_mfma_f32_16x16x32_bf16(af, b0, acc0, 0, 0, 0);
        acc1 = __builtin_amdgcn_mfma_f32_16x16x32_bf16(af, b1, acc1, 0, 0, 0);
    }
    // lane holds Wh[node0+4q+i][d=r] = acc0[i], Wh[node0+4q+i][d=16+r] = acc1[i]
    u32x4 pk = { cvt_pk_bf16(acc0[0], acc0[1]), cvt_pk_bf16(acc0[2], acc0[3]),
                 cvt_pk_bf16(acc1[0], acc1[1]), cvt_pk_bf16(acc1[2], acc1[3]) };
    unsigned long long lo = ((unsigned long long)pk[1] << 32) | pk[0];
    unsigned long long hi = ((unsigned long long)pk[3] << 32) | pk[2];
    *(unsigned long long*)&whT[((size_t)head * 32 + r) * 4096 + node0 + q * 4] = lo;
    *(unsigned long long*)&whT[((size_t)head * 32 + 16 + r) * 4096 + node0 + q * 4] = hi;

    // wh1/wh2 = Wh . a1/a2 over d; lane has d=r and d=16+r; reduce across r
    float a1lo = avec[head * 64 + r],      a1hi = avec[head * 64 + 16 + r];
    float a2lo = avec[head * 64 + 32 + r], a2hi = avec[head * 64 + 48 + r];
    f32x4 d1, d2;
    #pragma unroll
    for (int i = 0; i < 4; ++i) {
        d1[i] = fmaf(acc0[i], a1lo, acc1[i] * a1hi);
        d2[i] = fmaf(acc0[i], a2lo, acc1[i] * a2hi);
    }
    #pragma unroll
    for (int s = 1; s < 16; s <<= 1) {
        #pragma unroll
        for (int i = 0; i < 4; ++i) {
            d1[i] += __shfl_xor(d1[i], s);
            d2[i] += __shfl_xor(d2[i], s);
        }
    }
    if (r == 0) {
        f32x4 o1 = d1 * LOG2E, o2 = d2 * LOG2E;
        *(f32x4*)&wh1s[(size_t)head * 4096 + node0 + q * 4] = o1;
        *(f32x4*)&wh2s[(size_t)head * 4096 + node0 + q * 4] = o2;
    }
}

// ---------------- K2: fused masked softmax + PV via bf16 MFMA --------------
// r8 structure (flash-style LDS tiles) with T2-style XOR swizzle on whTl:
// linear [32][128] rows, 16B-slot index ^= (row&7) on BOTH write and read.
// Read groups (kk*4+q)^(r&7) spread 2 lanes/bank -> conflict-free (m136).
__global__ __launch_bounds__(256, 4) void k_attn(const unsigned long long* __restrict__ adj64, // [4096][64]
                                                 const float* __restrict__ wh1s,
                                                 const float* __restrict__ wh2s,
                                                 const unsigned short* __restrict__ whT,
                                                 float* __restrict__ out) {                    // [4096][256]
    const int head = blockIdx.y;
    const int rowbase = blockIdx.x * 32;
    const int t = threadIdx.x;
    const int w = t >> 6;
    const int lane = t & 63;
    const int rt = w & 1;        // row-tile
    const int jh = w >> 1;       // j-half
    const int r = lane & 15;     // MFMA A row / B col
    const int q = lane >> 4;     // k-quarter
    const int row = rowbase + rt * 16 + r;

    __shared__ unsigned short whTl[2][32][128];   // [half][d][j], XOR-swizzled 16B slots
    __shared__ float wh2t[2][128];
    __shared__ float wmxb[4];
    __shared__ f32x4 red[2][64][3];

    // per-head max of wh2 (r7-validated prepass)
    const float* wh2p = &wh2s[(size_t)head * 4096];
    float lm = -INFINITY;
    #pragma unroll
    for (int kk = 0; kk < 4; ++kk) {
        float4 v = *(const float4*)&wh2p[kk * 1024 + t * 4];
        lm = fmaxf(fmaxf(lm, fmaxf(v.x, v.y)), fmaxf(v.z, v.w));
    }
    #pragma unroll
    for (int s = 1; s < 64; s <<= 1) lm = fmaxf(lm, __shfl_xor(lm, s));
    if (lane == 0) wmxb[w] = lm;
    __syncthreads();
    const float wm = fmaxf(fmaxf(wmxb[0], wmxb[1]), fmaxf(wmxb[2], wmxb[3]));

    // per-row constants (r6-validated math, log2-scaled domain)
    const float wh1 = wh1s[(size_t)head * 4096 + row];
    const float sm0 = wh1 + wm;
    const float m = fmaxf(sm0, GAT_ALPHA * sm0);
    const float wh1m = wh1 - m;
    const float c2 = GAT_ALPHA * wh1 - m;

    f32x4 acc0 = {0.f, 0.f, 0.f, 0.f};
    f32x4 acc1 = {0.f, 0.f, 0.f, 0.f};
    f32x4 accd = {0.f, 0.f, 0.f, 0.f};

    const u32x4 onesu = {0x3F803F80u, 0x3F803F80u, 0x3F803F80u, 0x3F803F80u};
    const bf16x8 ones = __builtin_bit_cast(bf16x8, onesu);

    // staging indices: thread t loads d-row sd, two 16B slots (2sc, 2sc+1)
    const int sd = t >> 3;
    const int sc = t & 7;
    const unsigned short* gwh = &whT[((size_t)head * 32 + sd) * 4096 + sc * 16];
    const unsigned long long* arow = adj64 + (size_t)row * 64 + jh * 32;

    for (int step = 0; step < 16; ++step) {
        __syncthreads();   // previous tile fully consumed
        #pragma unroll
        for (int hh = 0; hh < 2; ++hh) {
            const uint4* s = (const uint4*)&gwh[hh * 2048 + step * 128];
            uint4 v0 = s[0];
            uint4 v1 = s[1];
            *(uint4*)&whTl[hh][sd][((sc * 2) ^ (sd & 7)) * 8]     = v0;
            *(uint4*)&whTl[hh][sd][((sc * 2 + 1) ^ (sd & 7)) * 8] = v1;
        }
        if (t < 64) {
            int hh = t >> 5, ii = (t & 31) * 4;
            *(float4*)&wh2t[hh][ii] = *(const float4*)&wh2p[hh * 2048 + step * 128 + ii];
        }
        __syncthreads();   // tile ready

        const unsigned long long au0 = arow[step * 2];
        const unsigned long long au1 = arow[step * 2 + 1];

        #pragma unroll
        for (int kk = 0; kk < 4; ++kk) {
            const int jl = kk * 32 + q * 8;
            const int slot = ((kk * 4 + q) ^ (r & 7)) * 8;
            bf16x8 b0 = *(const bf16x8*)&whTl[jh][r][slot];
            bf16x8 b1 = *(const bf16x8*)&whTl[jh][16 + r][slot];
            unsigned int bits =
                (unsigned int)(((kk < 2 ? au0 : au1) >> ((kk & 1) * 32 + q * 8)) & 0xffull);
            float w2[8];
            *(float4*)&w2[0] = *(const float4*)&wh2t[jh][jl];
            *(float4*)&w2[4] = *(const float4*)&wh2t[jh][jl + 4];

            float p[8];
            #pragma unroll
            for (int b = 0; b < 8; ++b) {
                float u = wh1m + w2[b];                  // s - m   (s>0 case)
                float tv = fmaf(GAT_ALPHA, w2[b], c2);   // a*s - m (s<0 case)
                float s = fmaxf(u, tv);                  // lrelu(s) - m, <= 0
                float pe = EXP2F(s);
                p[b] = (bits & (1u << b)) ? pe : 0.f;    // mask
            }
            u32x4 pk = { cvt_pk_bf16(p[0], p[1]), cvt_pk_bf16(p[2], p[3]),
                         cvt_pk_bf16(p[4], p[5]), cvt_pk_bf16(p[6], p[7]) };
            bf16x8 af = __builtin_bit_cast(bf16x8, pk);
            acc0 = __builtin_amdgcn_mfma_f32_16x16x32_bf16(af, b0, acc0, 0, 0, 0);
            acc1 = __builtin_amdgcn_mfma_f32_16x16x32_bf16(af, b1, acc1, 0, 0, 0);
            accd = __builtin_amdgcn_mfma_f32_16x16x32_bf16(af, ones, accd, 0, 0, 0);
        }
    }

    // combine j-halves (r2-validated): jh=1 publish, jh=0 finalize
    if (jh == 1) {
        red[rt][lane][0] = acc0;
        red[rt][lane][1] = acc1;
        red[rt][lane][2] = accd;
    }
    __syncthreads();
    if (jh == 0) {
        acc0 += red[rt][lane][0];
        acc1 += red[rt][lane][1];
        accd += red[rt][lane][2];
        // C/D layout (m89-verified): lane holds D[4q+i][r]
        #pragma unroll
        for (int i = 0; i < 4; ++i) {
            float inv = 1.0f / accd[i];
            int orow = rowbase + rt * 16 + 4 * q + i;
            out[(size_t)orow * 256 + head * 32 + r]      = acc0[i] * inv;
            out[(size_t)orow * 256 + head * 32 + 16 + r] = acc1[i] * inv;
        }
    }
}

extern "C" void kernel_launch(void* const* d_in, const int* in_sizes, int n_in,
                              void* d_out, int out_size, void* d_ws, size_t ws_size,
                              hipStream_t stream) {
    const float* h   = (const float*)d_in[0];
    const int*   adj = (const int*)d_in[1];
    const float* W   = (const float*)d_in[2];
    const float* a   = (const float*)d_in[3];
    float* out = (float*)d_out;

    char* ws = (char*)d_ws;
    unsigned long long* packed = (unsigned long long*)ws;                        // 2 MB
    float* wh1s = (float*)(ws + (2 << 20));                                      // 128 KB
    float* wh2s = (float*)(ws + (2 << 20) + (128 << 10));                        // 128 KB
    unsigned short* whT  = (unsigned short*)(ws + (2 << 20) + (256 << 10));      // 2 MB
    unsigned short* wbfT = (unsigned short*)(ws + (4 << 20) + (256 << 10));      // 128 KB

    const int nwords = 4096 * 64;
    k_pack_adj<<<nwords * 64 / 256, 256, 0, stream>>>(adj, packed, nwords);
    k_cvtW<<<32, 256, 0, stream>>>(W, wbfT);
    k_wh2<<<dim3(64, 8), 256, 0, stream>>>(h, wbfT, a, wh1s, wh2s, whT);
    k_attn<<<dim3(128, 8), 256, 0, stream>>>(packed, wh1s, wh2s, whT, out);
}

// Round 10
// 85.542 us; speedup vs baseline: 1.7016x; 1.0130x over previous
//
#include <hip/hip_runtime.h>
#include <hip/hip_bf16.h>
#include <stdint.h>

#define GAT_ALPHA 0.2f
#define LOG2E 1.4426950408889634f

typedef __attribute__((ext_vector_type(8))) short bf16x8;
typedef __attribute__((ext_vector_type(8))) unsigned short ushort8;
typedef __attribute__((ext_vector_type(4))) float f32x4;
typedef __attribute__((ext_vector_type(4))) unsigned int u32x4;

#if __has_builtin(__builtin_amdgcn_exp2f)
#define EXP2F(x) __builtin_amdgcn_exp2f(x)
#else
#define EXP2F(x) exp2f(x)
#endif

// D.lo = bf16(a), D.hi = bf16(b)  (r6-validated)
static __device__ __forceinline__ unsigned int cvt_pk_bf16(float a, float b) {
    unsigned int r;
    asm("v_cvt_pk_bf16_f32 %0, %1, %2" : "=v"(r) : "v"(a), "v"(b));
    return r;
}

// async global->LDS, 16B/lane; dest = wave-uniform base + lane*16 (m104),
// source is PER-LANE (m173 pre-swizzled-source pattern)
static __device__ __forceinline__ void gl16(const void* g, void* l) {
    __builtin_amdgcn_global_load_lds((const __attribute__((address_space(1))) void*)g,
                                     (__attribute__((address_space(3))) void*)l, 16, 0, 0);
}

// ---------------- K0: pack adjacency int32 -> bitmask (validated r1) -------
__global__ __launch_bounds__(256) void k_pack_adj(const int* __restrict__ adj,
                                                  unsigned long long* __restrict__ packed,
                                                  int nwords) {
    int gid = blockIdx.x * 256 + threadIdx.x;
    int wid = gid >> 6;               // one 64-bit word per wave
    int lane = threadIdx.x & 63;
    if (wid >= nwords) return;
    int v = adj[(size_t)wid * 64 + lane];
    unsigned long long m = __ballot(v > 0);
    if (lane == 0) packed[wid] = m;
}

// ---------------- K0b: W [8][256][32] f32 -> wbfT [8][32][256] bf16 (r9) ---
__global__ __launch_bounds__(256) void k_cvtW(const float* __restrict__ W,
                                              unsigned short* __restrict__ wbfT) {
    int idx = (blockIdx.x * 256 + threadIdx.x) * 8;   // over 65536 elements
    int hd = idx >> 8;                                 // head*32 + d
    int i0 = idx & 255;
    int hh = hd >> 5, dd = hd & 31;
    float v[8];
    #pragma unroll
    for (int k = 0; k < 8; ++k) v[k] = W[((size_t)hh * 256 + i0 + k) * 32 + dd];
    u32x4 o = { cvt_pk_bf16(v[0], v[1]), cvt_pk_bf16(v[2], v[3]),
                cvt_pk_bf16(v[4], v[5]), cvt_pk_bf16(v[6], v[7]) };
    *(u32x4*)&wbfT[idx] = o;
}

// ---------------- K1: Wh via bf16 MFMA (validated r9) ----------------------
__global__ __launch_bounds__(256) void k_wh2(const float* __restrict__ hmat,      // [4096][256]
                                             const unsigned short* __restrict__ wbfT, // [8][32][256]
                                             const float* __restrict__ avec,      // [8][64]
                                             float* __restrict__ wh1s,            // [8][4096] *log2e
                                             float* __restrict__ wh2s,            // [8][4096] *log2e
                                             unsigned short* __restrict__ whT) {  // [8][32][4096]
    const int head = blockIdx.y;
    const int nbase = blockIdx.x * 64;
    const int t = threadIdx.x, w = t >> 6, lane = t & 63;
    const int r = lane & 15, q = lane >> 4;
    const int node0 = nbase + w * 16;

    f32x4 acc0 = {0.f, 0.f, 0.f, 0.f};
    f32x4 acc1 = {0.f, 0.f, 0.f, 0.f};
    const float* arow = &hmat[(size_t)(node0 + r) * 256];
    const unsigned short* b0p = &wbfT[((size_t)head * 32 + r) * 256];
    const unsigned short* b1p = b0p + 16 * 256;
    #pragma unroll
    for (int kt = 0; kt < 8; ++kt) {
        const int ko = kt * 32 + q * 8;
        float4 h0 = *(const float4*)&arow[ko];
        float4 h1 = *(const float4*)&arow[ko + 4];
        u32x4 ap = { cvt_pk_bf16(h0.x, h0.y), cvt_pk_bf16(h0.z, h0.w),
                     cvt_pk_bf16(h1.x, h1.y), cvt_pk_bf16(h1.z, h1.w) };
        bf16x8 af = __builtin_bit_cast(bf16x8, ap);
        bf16x8 b0 = *(const bf16x8*)&b0p[ko];
        bf16x8 b1 = *(const bf16x8*)&b1p[ko];
        acc0 = __builtin_amdgcn_mfma_f32_16x16x32_bf16(af, b0, acc0, 0, 0, 0);
        acc1 = __builtin_amdgcn_mfma_f32_16x16x32_bf16(af, b1, acc1, 0, 0, 0);
    }
    u32x4 pk = { cvt_pk_bf16(acc0[0], acc0[1]), cvt_pk_bf16(acc0[2], acc0[3]),
                 cvt_pk_bf16(acc1[0], acc1[1]), cvt_pk_bf16(acc1[2], acc1[3]) };
    unsigned long long lo = ((unsigned long long)pk[1] << 32) | pk[0];
    unsigned long long hi = ((unsigned long long)pk[3] << 32) | pk[2];
    *(unsigned long long*)&whT[((size_t)head * 32 + r) * 4096 + node0 + q * 4] = lo;
    *(unsigned long long*)&whT[((size_t)head * 32 + 16 + r) * 4096 + node0 + q * 4] = hi;

    float a1lo = avec[head * 64 + r],      a1hi = avec[head * 64 + 16 + r];
    float a2lo = avec[head * 64 + 32 + r], a2hi = avec[head * 64 + 48 + r];
    f32x4 d1, d2;
    #pragma unroll
    for (int i = 0; i < 4; ++i) {
        d1[i] = fmaf(acc0[i], a1lo, acc1[i] * a1hi);
        d2[i] = fmaf(acc0[i], a2lo, acc1[i] * a2hi);
    }
    #pragma unroll
    for (int s = 1; s < 16; s <<= 1) {
        #pragma unroll
        for (int i = 0; i < 4; ++i) {
            d1[i] += __shfl_xor(d1[i], s);
            d2[i] += __shfl_xor(d2[i], s);
        }
    }
    if (r == 0) {
        f32x4 o1 = d1 * LOG2E, o2 = d2 * LOG2E;
        *(f32x4*)&wh1s[(size_t)head * 4096 + node0 + q * 4] = o1;
        *(f32x4*)&wh2s[(size_t)head * 4096 + node0 + q * 4] = o2;
    }
}

// ---------------- K2: fused masked softmax + PV via bf16 MFMA --------------
// r9 structure, staging via global_load_lds (linear LDS dest, pre-swizzled
// per-lane global source: phys slot p of row d holds linear slot
// ls = (p&8)|((p^d)&7)) + double-buffered single-barrier pipeline (T3-min).
// Read path byte-identical to r9. LDS ~34.8KB -> 4 blocks/CU.
__global__ __launch_bounds__(256, 4) void k_attn(const unsigned long long* __restrict__ adj64, // [4096][64]
                                                 const float* __restrict__ wh1s,
                                                 const float* __restrict__ wh2s,
                                                 const unsigned short* __restrict__ whT,
                                                 float* __restrict__ out) {                    // [4096][256]
    const int head = blockIdx.y;
    const int rowbase = blockIdx.x * 32;
    const int t = threadIdx.x;
    const int w = t >> 6;
    const int lane = t & 63;
    const int rt = w & 1;        // row-tile
    const int jh = w >> 1;       // j-half
    const int r = lane & 15;     // MFMA A row / B col
    const int q = lane >> 4;     // k-quarter
    const int row = rowbase + rt * 16 + r;

    __shared__ unsigned short whTl[2][2][32][128];   // [buf][jhalf][d][phys slots]
    __shared__ float wh2t[2][2][128];                // [buf][jhalf][j]
    __shared__ float wmxb[4];

    // per-lane pre-swizzled global sources for this wave's 4 staging calls
    const int ghh = w >> 1;          // j-half this wave stages
    const int grg = (w & 1) * 4;     // row-group base
    const unsigned short* gsrc[4];
    #pragma unroll
    for (int c = 0; c < 4; ++c) {
        int d = (grg + c) * 4 + (lane >> 4);
        int p = lane & 15;
        int ls = (p & 8) | ((p ^ d) & 7);
        gsrc[c] = whT + ((size_t)(head * 32 + d)) * 4096 + ghh * 2048 + ls * 8;
    }
    const float* wh2p = &wh2s[(size_t)head * 4096];
    const float* wh2src = wh2p + (lane >> 5) * 2048 + (lane & 31) * 4;

    // prologue: stage step 0 into buf 0 (latency hidden under prepass)
    #pragma unroll
    for (int c = 0; c < 4; ++c)
        gl16(gsrc[c], &whTl[0][ghh][(grg + c) * 4][0]);
    if (w == 0) gl16(wh2src, &wh2t[0][0][0]);

    // per-head max of wh2 (r7-validated prepass)
    float lm = -INFINITY;
    #pragma unroll
    for (int kk = 0; kk < 4; ++kk) {
        float4 v = *(const float4*)&wh2p[kk * 1024 + t * 4];
        lm = fmaxf(fmaxf(lm, fmaxf(v.x, v.y)), fmaxf(v.z, v.w));
    }
    #pragma unroll
    for (int s = 1; s < 64; s <<= 1) lm = fmaxf(lm, __shfl_xor(lm, s));
    if (lane == 0) wmxb[w] = lm;
    __syncthreads();   // wmxb ready; stage-0 drained (compiler vmcnt before barrier)
    const float wm = fmaxf(fmaxf(wmxb[0], wmxb[1]), fmaxf(wmxb[2], wmxb[3]));

    // per-row constants (r6-validated math, log2-scaled domain)
    const float wh1 = wh1s[(size_t)head * 4096 + row];
    const float sm0 = wh1 + wm;
    const float m = fmaxf(sm0, GAT_ALPHA * sm0);
    const float wh1m = wh1 - m;
    const float c2 = GAT_ALPHA * wh1 - m;

    f32x4 acc0 = {0.f, 0.f, 0.f, 0.f};
    f32x4 acc1 = {0.f, 0.f, 0.f, 0.f};
    f32x4 accd = {0.f, 0.f, 0.f, 0.f};

    const u32x4 onesu = {0x3F803F80u, 0x3F803F80u, 0x3F803F80u, 0x3F803F80u};
    const bf16x8 ones = __builtin_bit_cast(bf16x8, onesu);

    const unsigned long long* arow = adj64 + (size_t)row * 64 + jh * 32;
    unsigned long long au0 = arow[0], au1 = arow[1];
    int cur = 0;

    for (int step = 0; step < 16; ++step) {
        unsigned long long an0 = 0, an1 = 0;
        if (step < 15) {   // issue next-tile stage (consumed after this step's barrier)
            #pragma unroll
            for (int c = 0; c < 4; ++c)
                gl16(gsrc[c] + (step + 1) * 128, &whTl[cur ^ 1][ghh][(grg + c) * 4][0]);
            if (w == 0) gl16(wh2src + (step + 1) * 128, &wh2t[cur ^ 1][0][0]);
            an0 = arow[(step + 1) * 2];
            an1 = arow[(step + 1) * 2 + 1];
        }

        #pragma unroll
        for (int kk = 0; kk < 4; ++kk) {
            const int jl = kk * 32 + q * 8;
            const int slot = ((kk * 4 + q) ^ (r & 7)) * 8;   // r9-validated read map
            bf16x8 b0 = *(const bf16x8*)&whTl[cur][jh][r][slot];
            bf16x8 b1 = *(const bf16x8*)&whTl[cur][jh][16 + r][slot];
            unsigned int bits =
                (unsigned int)(((kk < 2 ? au0 : au1) >> ((kk & 1) * 32 + q * 8)) & 0xffull);
            float w2[8];
            *(float4*)&w2[0] = *(const float4*)&wh2t[cur][jh][jl];
            *(float4*)&w2[4] = *(const float4*)&wh2t[cur][jh][jl + 4];

            float p[8];
            #pragma unroll
            for (int b = 0; b < 8; ++b) {
                float u = wh1m + w2[b];                  // s - m   (s>0 case)
                float tv = fmaf(GAT_ALPHA, w2[b], c2);   // a*s - m (s<0 case)
                float s = fmaxf(u, tv);                  // lrelu(s) - m, <= 0
                float pe = EXP2F(s);
                p[b] = (bits & (1u << b)) ? pe : 0.f;    // mask
            }
            u32x4 pk = { cvt_pk_bf16(p[0], p[1]), cvt_pk_bf16(p[2], p[3]),
                         cvt_pk_bf16(p[4], p[5]), cvt_pk_bf16(p[6], p[7]) };
            bf16x8 af = __builtin_bit_cast(bf16x8, pk);
            acc0 = __builtin_amdgcn_mfma_f32_16x16x32_bf16(af, b0, acc0, 0, 0, 0);
            acc1 = __builtin_amdgcn_mfma_f32_16x16x32_bf16(af, b1, acc1, 0, 0, 0);
            accd = __builtin_amdgcn_mfma_f32_16x16x32_bf16(af, ones, accd, 0, 0, 0);
        }

        __syncthreads();   // stage(s+1) drained + all waves done with buf[cur]
        au0 = an0;
        au1 = an1;
        cur ^= 1;
    }

    // combine j-halves; red overlaid on dead whTl (saves 6KB -> keeps 4 blk/CU)
    f32x4* red = (f32x4*)whTl;
    if (jh == 1) {
        f32x4* rp = red + (rt * 64 + lane) * 3;
        rp[0] = acc0;
        rp[1] = acc1;
        rp[2] = accd;
    }
    __syncthreads();
    if (jh == 0) {
        const f32x4* rp = red + (rt * 64 + lane) * 3;
        acc0 += rp[0];
        acc1 += rp[1];
        accd += rp[2];
        // C/D layout (m89-verified): lane holds D[4q+i][r]
        #pragma unroll
        for (int i = 0; i < 4; ++i) {
            float inv = 1.0f / accd[i];
            int orow = rowbase + rt * 16 + 4 * q + i;
            out[(size_t)orow * 256 + head * 32 + r]      = acc0[i] * inv;
            out[(size_t)orow * 256 + head * 32 + 16 + r] = acc1[i] * inv;
        }
    }
}

extern "C" void kernel_launch(void* const* d_in, const int* in_sizes, int n_in,
                              void* d_out, int out_size, void* d_ws, size_t ws_size,
                              hipStream_t stream) {
    const float* h   = (const float*)d_in[0];
    const int*   adj = (const int*)d_in[1];
    const float* W   = (const float*)d_in[2];
    const float* a   = (const float*)d_in[3];
    float* out = (float*)d_out;

    char* ws = (char*)d_ws;
    unsigned long long* packed = (unsigned long long*)ws;                        // 2 MB
    float* wh1s = (float*)(ws + (2 << 20));                                      // 128 KB
    float* wh2s = (float*)(ws + (2 << 20) + (128 << 10));                        // 128 KB
    unsigned short* whT  = (unsigned short*)(ws + (2 << 20) + (256 << 10));      // 2 MB
    unsigned short* wbfT = (unsigned short*)(ws + (4 << 20) + (256 << 10));      // 128 KB

    const int nwords = 4096 * 64;
    k_pack_adj<<<nwords * 64 / 256, 256, 0, stream>>>(adj, packed, nwords);
    k_cvtW<<<32, 256, 0, stream>>>(W, wbfT);
    k_wh2<<<dim3(64, 8), 256, 0, stream>>>(h, wbfT, a, wh1s, wh2s, whT);
    k_attn<<<dim3(128, 8), 256, 0, stream>>>(packed, wh1s, wh2s, whT, out);
}